// Round 4
// baseline (742.162 us; speedup 1.0000x reference)
//
#include <hip/hip_runtime.h>

typedef __attribute__((ext_vector_type(4))) float  f32x4;
typedef __attribute__((ext_vector_type(4))) float  float4v;
typedef __attribute__((ext_vector_type(4))) short  short4v;
typedef __attribute__((ext_vector_type(8))) short  short8v;
typedef __attribute__((ext_vector_type(8))) __bf16 bf16x8;

union Frag { short4v h[2]; short8v s8; };

__device__ __forceinline__ short f2bf(float f) {
  unsigned u = __builtin_bit_cast(unsigned, f);
  u = (u + 0x7fffu + ((u >> 16) & 1u)) >> 16;
  return (short)u;
}

__device__ __forceinline__ f32x4 mfma_bf16(const Frag& a, const Frag& b, f32x4 c) {
  return __builtin_amdgcn_mfma_f32_16x16x32_bf16(
      __builtin_bit_cast(bf16x8, a.s8), __builtin_bit_cast(bf16x8, b.s8), c, 0, 0, 0);
}

// ---------------------------------------------------------------- K0: weights
// wtq [576][192] bf16 (col-major of w_qkv), wto [192][192] bf16 (col-major of w_o)
__global__ __launch_bounds__(256) void k_transpose_w(
    const float* __restrict__ w_qkv, const float* __restrict__ w_o,
    short* __restrict__ wtq, short* __restrict__ wto) {
  int idx = blockIdx.x * 256 + threadIdx.x;
  if (idx < 110592) {
    int k = idx / 576, c = idx % 576;
    wtq[c * 192 + k] = f2bf(w_qkv[idx]);
  } else {
    int j = idx - 110592;
    int k = j / 192, c = j % 192;
    wto[c * 192 + k] = f2bf(w_o[j]);
  }
}

// ------------------------------------------------ K1: fused QKV-proj + attention
// ONE BLOCK PER b, looping h=0..5. Mask/x become L2-hot after head 0.
// XCD pair-swizzle: (b, b+512) share a mask window -> same XCD L2.
__global__ __launch_bounds__(256, 2) void k_fused(
    const float* __restrict__ x, const float* __restrict__ bqkv,
    const short* __restrict__ wtq, const float* __restrict__ mask,
    const float* __restrict__ btab, float* __restrict__ out) {
  __shared__ short q_lds[144][40];    // [n][d0..31]  (q pre-scaled)
  __shared__ short k_lds[144][40];    // [n][d]
  __shared__ short vT[32][152];       // [d][n]
  __shared__ short p_lds[144][152];   // [qrow][kcol]
  const int tid = threadIdx.x;
  const int lane = tid & 63, wv = tid >> 6;
  const int l15 = lane & 15, lg = lane >> 4;

  // dispatch id -> XCD-grouped virtual id (round-robin: xcd = id % 8)
  const int did = blockIdx.x;
  const int vid = (did & 7) * 128 + (did >> 3);   // 1024 blocks, 128 per XCD
  const int g = vid >> 1;                          // mask window 0..511
  const int b = g + (vid & 1) * 512;
  const int wm = g;

  // relative-position column codes (per lane, head-independent)
  int cn[9];
#pragma unroll
  for (int cf = 0; cf < 9; ++cf) {
    int n = cf * 16 + l15;
    cn[cf] = 11 * (n / 72) + ((n / 12) % 6) + (n % 12);
  }

  for (int h = 0; h < 6; ++h) {
    __syncthreads();   // previous head's phase-3 LDS reads done before overwrite

    // ---------------- phase 1: QKV projection for (b,h) into LDS
    for (int t = wv; t < 9; t += 4) {
      Frag ax[6];
#pragma unroll
      for (int kc = 0; kc < 6; ++kc) {   // x fragment, fp32 -> bf16
        const float* xr = &x[(size_t)(b * 144 + t * 16 + l15) * 192 + kc * 32 + lg * 4];
        float4v x0 = *(const float4v*)xr;
        float4v x1 = *(const float4v*)(xr + 16);
        ax[kc].h[0] = short4v{ f2bf(x0[0]), f2bf(x0[1]), f2bf(x0[2]), f2bf(x0[3]) };
        ax[kc].h[1] = short4v{ f2bf(x1[0]), f2bf(x1[1]), f2bf(x1[2]), f2bf(x1[3]) };
      }
#pragma unroll
      for (int pc = 0; pc < 6; ++pc) {
        const int p = pc >> 1, c = pc & 1;
        const int col = p * 192 + h * 32 + c * 16 + l15;
        f32x4 acc = {0.f, 0.f, 0.f, 0.f};
#pragma unroll
        for (int kc = 0; kc < 6; ++kc) {
          Frag bw;
          bw.h[0] = *(const short4v*)&wtq[col * 192 + kc * 32 + lg * 4];
          bw.h[1] = *(const short4v*)&wtq[col * 192 + kc * 32 + lg * 4 + 16];
          acc = mfma_bf16(ax[kc], bw, acc);
        }
        const float bias = bqkv[col];
        const float scl = (p == 0) ? 0.17677669529663687f : 1.0f;
        const int d = c * 16 + l15;
#pragma unroll
        for (int r = 0; r < 4; ++r) {
          const int row = t * 16 + lg * 4 + r;       // token index
          const short bv = f2bf((acc[r] + bias) * scl);
          if (p == 0)      q_lds[row][d] = bv;
          else if (p == 1) k_lds[row][d] = bv;
          else             vT[d][row]    = bv;
        }
      }
    }
    __syncthreads();

    // ---------------- phase 2: S = QK^T + bias + mask, softmax -> p_lds
    float rsum[3][4];
    for (int t = wv, ti = 0; t < 9; t += 4, ++ti) {
      Frag aq;
      aq.h[0] = *(const short4v*)&q_lds[t * 16 + l15][lg * 4];
      aq.h[1] = *(const short4v*)&q_lds[t * 16 + l15][lg * 4 + 16];
      f32x4 s[9];
#pragma unroll
      for (int cf = 0; cf < 9; ++cf) {
        Frag bk;
        bk.h[0] = *(const short4v*)&k_lds[cf * 16 + l15][lg * 4];
        bk.h[1] = *(const short4v*)&k_lds[cf * 16 + l15][lg * 4 + 16];
        s[cf] = mfma_bf16(aq, bk, f32x4{0.f, 0.f, 0.f, 0.f});
      }
      int cm[4];
#pragma unroll
      for (int j = 0; j < 4; ++j) {
        int m = t * 16 + lg * 4 + j;
        cm[j] = 11 * (m / 72) + ((m / 12) % 6) + (m % 12);
      }
#pragma unroll
      for (int cf = 0; cf < 9; ++cf) {
#pragma unroll
        for (int j = 0; j < 4; ++j) {
          int m = t * 16 + lg * 4 + j;
          int n = cf * 16 + l15;
          s[cf][j] += btab[(cm[j] - cn[cf] + 27) * 6 + h]
                    + mask[(size_t)wm * 20736 + m * 144 + n];
        }
      }
#pragma unroll
      for (int j = 0; j < 4; ++j) {
        float mx = s[0][j];
#pragma unroll
        for (int cf = 1; cf < 9; ++cf) mx = fmaxf(mx, s[cf][j]);
        mx = fmaxf(mx, __shfl_xor(mx, 1, 64));
        mx = fmaxf(mx, __shfl_xor(mx, 2, 64));
        mx = fmaxf(mx, __shfl_xor(mx, 4, 64));
        mx = fmaxf(mx, __shfl_xor(mx, 8, 64));
        float sum = 0.f;
#pragma unroll
        for (int cf = 0; cf < 9; ++cf) {
          float e = __expf(s[cf][j] - mx);
          s[cf][j] = e;
          sum += e;
        }
        sum += __shfl_xor(sum, 1, 64);
        sum += __shfl_xor(sum, 2, 64);
        sum += __shfl_xor(sum, 4, 64);
        sum += __shfl_xor(sum, 8, 64);
        rsum[ti][j] = 1.0f / sum;
      }
#pragma unroll
      for (int cf = 0; cf < 9; ++cf)
#pragma unroll
        for (int j = 0; j < 4; ++j)
          p_lds[t * 16 + lg * 4 + j][cf * 16 + l15] = f2bf(s[cf][j]);
    }

    // ---------------- phase 3: O = P V  (each wave reads only tiles it wrote)
    for (int t = wv, ti = 0; t < 9; t += 4, ++ti) {
      f32x4 o0 = {0.f, 0.f, 0.f, 0.f}, o1 = {0.f, 0.f, 0.f, 0.f};
      for (int kc = 0; kc < 5; ++kc) {
        Frag ap, b0, b1;
        ap.h[0] = *(const short4v*)&p_lds[t * 16 + l15][kc * 32 + lg * 4];
        b0.h[0] = *(const short4v*)&vT[l15][kc * 32 + lg * 4];
        b1.h[0] = *(const short4v*)&vT[16 + l15][kc * 32 + lg * 4];
        if (kc < 4) {
          ap.h[1] = *(const short4v*)&p_lds[t * 16 + l15][kc * 32 + lg * 4 + 16];
          b0.h[1] = *(const short4v*)&vT[l15][kc * 32 + lg * 4 + 16];
          b1.h[1] = *(const short4v*)&vT[16 + l15][kc * 32 + lg * 4 + 16];
        } else {                  // K=144: zero the 144..159 half-step (both operands)
          ap.h[1] = short4v{0, 0, 0, 0};
          b0.h[1] = short4v{0, 0, 0, 0};
          b1.h[1] = short4v{0, 0, 0, 0};
        }
        o0 = mfma_bf16(ap, b0, o0);
        o1 = mfma_bf16(ap, b1, o1);
      }
#pragma unroll
      for (int r = 0; r < 4; ++r) {
        const int m = t * 16 + lg * 4 + r;
        const size_t base = (size_t)(b * 144 + m) * 192 + h * 32;
        out[base + l15]      = o0[r] * rsum[ti][r];
        out[base + 16 + l15] = o1[r] * rsum[ti][r];
      }
    }
  }
}

// ---------------------------------------------------------------- K2: out proj (in-place)
__global__ __launch_bounds__(256, 2) void k_oproj(
    float* __restrict__ io, const float* __restrict__ bo,
    const short* __restrict__ wto) {
  __shared__ short a_lds[64][200];
  __shared__ short bT[192][40];
  const int tid = threadIdx.x;
  const int lane = tid & 63, wv = tid >> 6;
  const int l15 = lane & 15, lg = lane >> 4;
  const int row0 = blockIdx.x * 64;

#pragma unroll
  for (int i = 0; i < 12; ++i) {
    int flat = tid + 256 * i;               // 64 rows x 48 float4 chunks
    int r = flat / 48, c4 = flat % 48;
    float4v xv = *(const float4v*)&io[(size_t)(row0 + r) * 192 + c4 * 4];
    short4v sv = { f2bf(xv[0]), f2bf(xv[1]), f2bf(xv[2]), f2bf(xv[3]) };
    *(short4v*)&a_lds[r][c4 * 4] = sv;
  }

  f32x4 acc[12];
#pragma unroll
  for (int i = 0; i < 12; ++i) acc[i] = f32x4{0.f, 0.f, 0.f, 0.f};

  for (int kc = 0; kc < 6; ++kc) {
    __syncthreads();
    // stage the FULL 32-wide K-chunk for all 192 columns (8 quads each)
#pragma unroll
    for (int i = 0; i < 6; ++i) {
      int flat = tid + 256 * i;             // < 1536
      int c = flat >> 3, kk = (flat & 7) << 2;
      *(short4v*)&bT[c][kk] = *(const short4v*)&wto[c * 192 + kc * 32 + kk];
    }
    __syncthreads();
    Frag a;
    a.h[0] = *(const short4v*)&a_lds[wv * 16 + l15][kc * 32 + lg * 4];
    a.h[1] = *(const short4v*)&a_lds[wv * 16 + l15][kc * 32 + lg * 4 + 16];
#pragma unroll
    for (int cf = 0; cf < 12; ++cf) {
      Frag bw;
      bw.h[0] = *(const short4v*)&bT[cf * 16 + l15][lg * 4];
      bw.h[1] = *(const short4v*)&bT[cf * 16 + l15][lg * 4 + 16];
      acc[cf] = mfma_bf16(a, bw, acc[cf]);
    }
  }

#pragma unroll
  for (int cf = 0; cf < 12; ++cf) {
    int c = cf * 16 + l15;
    float bias = bo[c];
#pragma unroll
    for (int r = 0; r < 4; ++r) {
      int g = row0 + wv * 16 + lg * 4 + r;
      io[(size_t)g * 192 + c] = acc[cf][r] + bias;
    }
  }
}

extern "C" void kernel_launch(void* const* d_in, const int* in_sizes, int n_in,
                              void* d_out, int out_size, void* d_ws, size_t ws_size,
                              hipStream_t stream) {
  const float* x    = (const float*)d_in[0];
  const float* mask = (const float*)d_in[1];
  const float* wqkv = (const float*)d_in[2];
  const float* bqkv = (const float*)d_in[3];
  const float* wo   = (const float*)d_in[4];
  const float* bo   = (const float*)d_in[5];
  const float* btab = (const float*)d_in[6];
  float* out = (float*)d_out;

  short* wtq = (short*)d_ws;                 // 110592 shorts
  short* wto = (short*)d_ws + 110592;        //  36864 shorts  (total ws: 295 KB)

  k_transpose_w<<<576, 256, 0, stream>>>(wqkv, wo, wtq, wto);
  k_fused<<<1024, 256, 0, stream>>>(x, bqkv, wtq, mask, btab, out);
  k_oproj<<<2304, 256, 0, stream>>>(out, bo, wto);
}

// Round 5
// 646.658 us; speedup vs baseline: 1.1477x; 1.1477x over previous
//
#include <hip/hip_runtime.h>

typedef __attribute__((ext_vector_type(4))) float  f32x4;
typedef __attribute__((ext_vector_type(4))) float  float4v;
typedef __attribute__((ext_vector_type(4))) short  short4v;
typedef __attribute__((ext_vector_type(8))) short  short8v;
typedef __attribute__((ext_vector_type(8))) __bf16 bf16x8;

union Frag { short4v h[2]; short8v s8; };

__device__ __forceinline__ short f2bf(float f) {
  unsigned u = __builtin_bit_cast(unsigned, f);
  u = (u + 0x7fffu + ((u >> 16) & 1u)) >> 16;
  return (short)u;
}

__device__ __forceinline__ f32x4 mfma_bf16(const Frag& a, const Frag& b, f32x4 c) {
  return __builtin_amdgcn_mfma_f32_16x16x32_bf16(
      __builtin_bit_cast(bf16x8, a.s8), __builtin_bit_cast(bf16x8, b.s8), c, 0, 0, 0);
}

__device__ __forceinline__ int poscode(int i) {   // 11*(i/72) + (i/12)%6 + i%12
  int z = (i >= 72) ? 1 : 0;
  int rem = i - 72 * z;
  int y = rem / 12;
  return 11 * z + y + (rem - 12 * y);
}

// ---------------------------------------------------------------- K0: weights
// wtq [576][192] bf16 (col-major of w_qkv), wto [192][192] bf16 (col-major of w_o)
__global__ __launch_bounds__(256) void k_transpose_w(
    const float* __restrict__ w_qkv, const float* __restrict__ w_o,
    short* __restrict__ wtq, short* __restrict__ wto) {
  int idx = blockIdx.x * 256 + threadIdx.x;
  if (idx < 110592) {
    int k = idx / 576, c = idx % 576;
    wtq[c * 192 + k] = f2bf(w_qkv[idx]);
  } else {
    int j = idx - 110592;
    int k = j / 192, c = j % 192;
    wto[c * 192 + k] = f2bf(w_o[j]);
  }
}

// ------------------------------------------------ K1: fused QKV-proj + attention
// One block per (b,h). Swapped QK^T: S^T = mfma(K,Q) puts each q-row's k-slice
// lane-local -> in-register softmax (2 shuffles) and P feeds PV directly
// (16x16 C/D quad layout == A-fragment quad layout). LDS 32KB -> 4 blocks/CU.
__global__ __launch_bounds__(256, 4) void k_fused(
    const float* __restrict__ x, const float* __restrict__ bqkv,
    const short* __restrict__ wtq, const float* __restrict__ mask,
    const float* __restrict__ btab, float* __restrict__ out) {
  __shared__ short q_lds[144][40];    // [n][d0..31]  (q pre-scaled)
  __shared__ short k_lds[144][40];    // [n][d]
  __shared__ short vT[32][152];       // [d][n]
  const int tid = threadIdx.x;
  const int lane = tid & 63, wv = tid >> 6;
  const int l15 = lane & 15, lg = lane >> 4;

  // XCD swizzle: round-robin -> contiguous 768-block chunks per XCD;
  // within a chunk, 12 consecutive blocks share one mask window (b, b+512 x 6 heads).
  const int did = blockIdx.x;
  const int vid = (did & 7) * 768 + (did >> 3);
  const int g = vid / 12, r = vid - g * 12;
  const int b = g + (r >= 6 ? 512 : 0);
  const int h = (r >= 6) ? r - 6 : r;
  const int wm = g;

  // ---------------- phase 1: QKV projection for (b,h) into LDS
  for (int t = wv; t < 9; t += 4) {
    Frag ax[6];
#pragma unroll
    for (int kc = 0; kc < 6; ++kc) {   // x fragment, fp32 -> bf16
      const float* xr = &x[(size_t)(b * 144 + t * 16 + l15) * 192 + kc * 32 + lg * 4];
      float4v x0 = *(const float4v*)xr;
      float4v x1 = *(const float4v*)(xr + 16);
      ax[kc].h[0] = short4v{ f2bf(x0[0]), f2bf(x0[1]), f2bf(x0[2]), f2bf(x0[3]) };
      ax[kc].h[1] = short4v{ f2bf(x1[0]), f2bf(x1[1]), f2bf(x1[2]), f2bf(x1[3]) };
    }
#pragma unroll
    for (int pc = 0; pc < 6; ++pc) {
      const int p = pc >> 1, c = pc & 1;
      const int col = p * 192 + h * 32 + c * 16 + l15;
      f32x4 acc = {0.f, 0.f, 0.f, 0.f};
#pragma unroll
      for (int kc = 0; kc < 6; ++kc) {
        Frag bw;
        bw.h[0] = *(const short4v*)&wtq[col * 192 + kc * 32 + lg * 4];
        bw.h[1] = *(const short4v*)&wtq[col * 192 + kc * 32 + lg * 4 + 16];
        acc = mfma_bf16(ax[kc], bw, acc);
      }
      const float bias = bqkv[col];
      const float scl = (p == 0) ? 0.17677669529663687f : 1.0f;
      const int d = c * 16 + l15;
#pragma unroll
      for (int rr = 0; rr < 4; ++rr) {
        const int row = t * 16 + lg * 4 + rr;       // token index
        const short bv = f2bf((acc[rr] + bias) * scl);
        if (p == 0)      q_lds[row][d] = bv;
        else if (p == 1) k_lds[row][d] = bv;
        else             vT[d][row]    = bv;
      }
    }
  }
  __syncthreads();    // the ONLY barrier: LDS read-only from here on

  // per-lane k-codes (t-independent): cnb6[cf] = 6*poscode(cf*16 + lg*4);
  // within a reg-quad codes are exactly consecutive (k%12 in {0,4,8}).
  int cnb6[9];
#pragma unroll
  for (int cf = 0; cf < 9; ++cf) cnb6[cf] = 6 * poscode(cf * 16 + lg * 4);

  const float* maskw = &mask[(size_t)wm * 20736];

  // ---------------- phase 2+3 per q-tile t: swapped QK^T, softmax, PV
  for (int t = wv; t < 9; t += 4) {
    const int q = t * 16 + l15;                      // this lane's q-row
    Frag aq;                                         // B-operand: Q
    aq.h[0] = *(const short4v*)&q_lds[q][lg * 4];
    aq.h[1] = *(const short4v*)&q_lds[q][lg * 4 + 16];

    f32x4 s[9];                                      // s[cf][reg] = S[q][cf*16+lg*4+reg]
#pragma unroll
    for (int cf = 0; cf < 9; ++cf) {
      Frag bk;                                       // A-operand: K-tile rows
      bk.h[0] = *(const short4v*)&k_lds[cf * 16 + l15][lg * 4];
      bk.h[1] = *(const short4v*)&k_lds[cf * 16 + l15][lg * 4 + 16];
      s[cf] = mfma_bf16(bk, aq, f32x4{0.f, 0.f, 0.f, 0.f});
    }

    const int C0 = (poscode(q) + 27) * 6 + h;
#pragma unroll
    for (int cf = 0; cf < 9; ++cf) {
      float4v mv = *(const float4v*)&maskw[q * 144 + cf * 16 + lg * 4];
      const int i0 = C0 - cnb6[cf];
#pragma unroll
      for (int reg = 0; reg < 4; ++reg)
        s[cf][reg] += mv[reg] + btab[i0 - 6 * reg];
    }

    // in-register softmax over k (36 regs + lanes ^16, ^32)
    float mx = s[0][0];
#pragma unroll
    for (int cf = 0; cf < 9; ++cf)
#pragma unroll
      for (int reg = 0; reg < 4; ++reg) mx = fmaxf(mx, s[cf][reg]);
    mx = fmaxf(mx, __shfl_xor(mx, 16, 64));
    mx = fmaxf(mx, __shfl_xor(mx, 32, 64));
    float sum = 0.f;
#pragma unroll
    for (int cf = 0; cf < 9; ++cf)
#pragma unroll
      for (int reg = 0; reg < 4; ++reg) {
        float e = __expf(s[cf][reg] - mx);
        s[cf][reg] = e;
        sum += e;
      }
    sum += __shfl_xor(sum, 16, 64);
    sum += __shfl_xor(sum, 32, 64);
    const float rinv = 1.0f / sum;
#pragma unroll
    for (int cf = 0; cf < 9; ++cf)
#pragma unroll
      for (int reg = 0; reg < 4; ++reg) s[cf][reg] *= rinv;

    // PV: P fragments come straight from s[] (layout matches A-fragment)
    f32x4 o0 = {0.f, 0.f, 0.f, 0.f}, o1 = {0.f, 0.f, 0.f, 0.f};
#pragma unroll
    for (int kc = 0; kc < 5; ++kc) {
      Frag ap, b0, b1;
      ap.h[0] = short4v{ f2bf(s[2 * kc][0]), f2bf(s[2 * kc][1]),
                         f2bf(s[2 * kc][2]), f2bf(s[2 * kc][3]) };
      b0.h[0] = *(const short4v*)&vT[l15][kc * 32 + lg * 4];
      b1.h[0] = *(const short4v*)&vT[16 + l15][kc * 32 + lg * 4];
      if (kc < 4) {
        ap.h[1] = short4v{ f2bf(s[2 * kc + 1][0]), f2bf(s[2 * kc + 1][1]),
                           f2bf(s[2 * kc + 1][2]), f2bf(s[2 * kc + 1][3]) };
        b0.h[1] = *(const short4v*)&vT[l15][kc * 32 + lg * 4 + 16];
        b1.h[1] = *(const short4v*)&vT[16 + l15][kc * 32 + lg * 4 + 16];
      } else {                    // K=144: zero the 144..159 half-step
        ap.h[1] = short4v{0, 0, 0, 0};
        b0.h[1] = short4v{0, 0, 0, 0};
        b1.h[1] = short4v{0, 0, 0, 0};
      }
      o0 = mfma_bf16(ap, b0, o0);
      o1 = mfma_bf16(ap, b1, o1);
    }
#pragma unroll
    for (int rr = 0; rr < 4; ++rr) {
      const int m = t * 16 + lg * 4 + rr;
      const size_t base = (size_t)(b * 144 + m) * 192 + h * 32;
      out[base + l15]      = o0[rr];
      out[base + 16 + l15] = o1[rr];
    }
  }
}

// ---------------------------------------------------------------- K2: out proj (in-place)
__global__ __launch_bounds__(256, 2) void k_oproj(
    float* __restrict__ io, const float* __restrict__ bo,
    const short* __restrict__ wto) {
  __shared__ short a_lds[64][200];
  __shared__ short bT[192][40];
  const int tid = threadIdx.x;
  const int lane = tid & 63, wv = tid >> 6;
  const int l15 = lane & 15, lg = lane >> 4;
  const int row0 = blockIdx.x * 64;

#pragma unroll
  for (int i = 0; i < 12; ++i) {
    int flat = tid + 256 * i;               // 64 rows x 48 float4 chunks
    int r = flat / 48, c4 = flat % 48;
    float4v xv = *(const float4v*)&io[(size_t)(row0 + r) * 192 + c4 * 4];
    short4v sv = { f2bf(xv[0]), f2bf(xv[1]), f2bf(xv[2]), f2bf(xv[3]) };
    *(short4v*)&a_lds[r][c4 * 4] = sv;
  }

  f32x4 acc[12];
#pragma unroll
  for (int i = 0; i < 12; ++i) acc[i] = f32x4{0.f, 0.f, 0.f, 0.f};

  for (int kc = 0; kc < 6; ++kc) {
    __syncthreads();
    // stage the FULL 32-wide K-chunk for all 192 columns (8 quads each)
#pragma unroll
    for (int i = 0; i < 6; ++i) {
      int flat = tid + 256 * i;             // < 1536
      int c = flat >> 3, kk = (flat & 7) << 2;
      *(short4v*)&bT[c][kk] = *(const short4v*)&wto[c * 192 + kc * 32 + kk];
    }
    __syncthreads();
    Frag a;
    a.h[0] = *(const short4v*)&a_lds[wv * 16 + l15][kc * 32 + lg * 4];
    a.h[1] = *(const short4v*)&a_lds[wv * 16 + l15][kc * 32 + lg * 4 + 16];
#pragma unroll
    for (int cf = 0; cf < 12; ++cf) {
      Frag bw;
      bw.h[0] = *(const short4v*)&bT[cf * 16 + l15][lg * 4];
      bw.h[1] = *(const short4v*)&bT[cf * 16 + l15][lg * 4 + 16];
      acc[cf] = mfma_bf16(a, bw, acc[cf]);
    }
  }

#pragma unroll
  for (int cf = 0; cf < 12; ++cf) {
    int c = cf * 16 + l15;
    float bias = bo[c];
#pragma unroll
    for (int r = 0; r < 4; ++r) {
      int g = row0 + wv * 16 + lg * 4 + r;
      io[(size_t)g * 192 + c] = acc[cf][r] + bias;
    }
  }
}

extern "C" void kernel_launch(void* const* d_in, const int* in_sizes, int n_in,
                              void* d_out, int out_size, void* d_ws, size_t ws_size,
                              hipStream_t stream) {
  const float* x    = (const float*)d_in[0];
  const float* mask = (const float*)d_in[1];
  const float* wqkv = (const float*)d_in[2];
  const float* bqkv = (const float*)d_in[3];
  const float* wo   = (const float*)d_in[4];
  const float* bo   = (const float*)d_in[5];
  const float* btab = (const float*)d_in[6];
  float* out = (float*)d_out;

  short* wtq = (short*)d_ws;                 // 110592 shorts
  short* wto = (short*)d_ws + 110592;        //  36864 shorts  (total ws: 295 KB)

  k_transpose_w<<<576, 256, 0, stream>>>(wqkv, wo, wtq, wto);
  k_fused<<<6144, 256, 0, stream>>>(x, bqkv, wtq, mask, btab, out);
  k_oproj<<<2304, 256, 0, stream>>>(out, bo, wto);
}

// Round 6
// 320.532 us; speedup vs baseline: 2.3154x; 2.0175x over previous
//
#include <hip/hip_runtime.h>

typedef __attribute__((ext_vector_type(4))) float  f32x4;
typedef __attribute__((ext_vector_type(4))) float  float4v;
typedef __attribute__((ext_vector_type(4))) short  short4v;
typedef __attribute__((ext_vector_type(8))) short  short8v;
typedef __attribute__((ext_vector_type(8))) __bf16 bf16x8;

union Frag { short4v h[2]; short8v s8; };

__device__ __forceinline__ short f2bf(float f) {
  unsigned u = __builtin_bit_cast(unsigned, f);
  u = (u + 0x7fffu + ((u >> 16) & 1u)) >> 16;
  return (short)u;
}

__device__ __forceinline__ f32x4 mfma_bf16(const Frag& a, const Frag& b, f32x4 c) {
  return __builtin_amdgcn_mfma_f32_16x16x32_bf16(
      __builtin_bit_cast(bf16x8, a.s8), __builtin_bit_cast(bf16x8, b.s8), c, 0, 0, 0);
}

__device__ __forceinline__ int poscode(int i) {   // 11*(i/72) + (i/12)%6 + i%12
  int z = (i >= 72) ? 1 : 0;
  int rem = i - 72 * z;
  int y = rem / 12;
  return 11 * z + y + (rem - 12 * y);
}

// ---------------------------------------------------------------- K0: weights
__global__ __launch_bounds__(256) void k_transpose_w(
    const float* __restrict__ w_qkv, const float* __restrict__ w_o,
    short* __restrict__ wtq, short* __restrict__ wto) {
  int idx = blockIdx.x * 256 + threadIdx.x;
  if (idx < 110592) {
    int k = idx / 576, c = idx % 576;
    wtq[c * 192 + k] = f2bf(w_qkv[idx]);
  } else {
    int j = idx - 110592;
    int k = j / 192, c = j % 192;
    wto[c * 192 + k] = f2bf(w_o[j]);
  }
}

// ---------------------------------------------------------------- K1: QKV GEMM
// C[147456][576] = x @ w_qkv + b; q pre-scaled; out bf16 [part][b][h][n][d]
__global__ __launch_bounds__(256, 2) void k_qkv(
    const float* __restrict__ x, const float* __restrict__ bqkv,
    const short* __restrict__ wtq, short* __restrict__ qkv) {
  __shared__ short a_lds[64][200];
  __shared__ short bT[576][40];
  const int tid = threadIdx.x;
  const int lane = tid & 63, wv = tid >> 6;
  const int l15 = lane & 15, lg = lane >> 4;
  const int row0 = blockIdx.x * 64;

#pragma unroll
  for (int i = 0; i < 12; ++i) {
    int flat = tid + 256 * i;               // 64 rows x 48 float4 chunks
    int r = flat / 48, c4 = flat % 48;
    float4v xv = *(const float4v*)&x[(size_t)(row0 + r) * 192 + c4 * 4];
    short4v sv = { f2bf(xv[0]), f2bf(xv[1]), f2bf(xv[2]), f2bf(xv[3]) };
    *(short4v*)&a_lds[r][c4 * 4] = sv;
  }

  f32x4 acc[36];
#pragma unroll
  for (int i = 0; i < 36; ++i) acc[i] = f32x4{0.f, 0.f, 0.f, 0.f};

  for (int kc = 0; kc < 6; ++kc) {
    __syncthreads();
    // FULL staging: 576 cols x 8 short4-quads = 4608 = 18 x 256
#pragma unroll
    for (int i = 0; i < 18; ++i) {
      int flat = tid + 256 * i;
      int c = flat >> 3, kk = (flat & 7) << 2;
      *(short4v*)&bT[c][kk] = *(const short4v*)&wtq[c * 192 + kc * 32 + kk];
    }
    __syncthreads();
    Frag a;
    a.h[0] = *(const short4v*)&a_lds[wv * 16 + l15][kc * 32 + lg * 4];
    a.h[1] = *(const short4v*)&a_lds[wv * 16 + l15][kc * 32 + lg * 4 + 16];
#pragma unroll
    for (int cf = 0; cf < 36; ++cf) {
      Frag bw;
      bw.h[0] = *(const short4v*)&bT[cf * 16 + l15][lg * 4];
      bw.h[1] = *(const short4v*)&bT[cf * 16 + l15][lg * 4 + 16];
      acc[cf] = mfma_bf16(a, bw, acc[cf]);
    }
  }

#pragma unroll
  for (int cf = 0; cf < 36; ++cf) {
    int c = cf * 16 + l15;
    int part = c / 192, rem = c % 192;
    int h = rem >> 5, d = rem & 31;
    float bias = bqkv[c];
    float scale = (part == 0) ? 0.17677669529663687f : 1.0f;
#pragma unroll
    for (int r = 0; r < 4; ++r) {
      int g = row0 + wv * 16 + lg * 4 + r;
      int b_ = g / 144, n = g - b_ * 144;
      float v = (acc[cf][r] + bias) * scale;
      qkv[(size_t)((part * 1024 + b_) * 6 + h) * 4608 + n * 32 + d] = f2bf(v);
    }
  }
}

// ---------------------------------------------------------------- K2: attention
// One 512-thread block per b. K/V^T for ALL 6 heads staged in LDS once;
// mask rows held fp32 in registers per q-tile, reused across 6 heads.
__global__ __launch_bounds__(512, 2) void k_attn(
    const short* __restrict__ qkv, const float* __restrict__ mask,
    const float* __restrict__ btab, float* __restrict__ out) {
  __shared__ short k_l[6][144][40];   // 69120 B
  __shared__ short vt[6][32][152];    // 58368 B  (total 127488 B)
  const int tid = threadIdx.x;
  const int lane = tid & 63, wv = tid >> 6;
  const int l15 = lane & 15, lg = lane >> 4;

  // pair-swizzle: (b, b+512) are 8 apart in launch order -> same XCD L2
  const int bid = blockIdx.x;
  const int b = ((bid >> 4) << 3) + (bid & 7) + (((bid >> 3) & 1) << 9);
  const int wm = b & 511;

  // ---- stage K all heads: 6*144*4 short8 units = 3456
  const size_t kbase = (size_t)(1024 + b) * 6 * 4608;
#pragma unroll
  for (int i = 0; i < 7; ++i) {
    int flat = tid + 512 * i;
    if (flat < 3456) {
      int h = flat / 576, r = flat % 576;
      int n = r >> 2, d8 = (r & 3) * 8;
      *(short8v*)&k_l[h][n][d8] =
          *(const short8v*)&qkv[kbase + (size_t)h * 4608 + n * 32 + d8];
    }
  }
  // ---- stage V^T all heads: 6*144*8 short4 units = 6912
  const size_t vbase = (size_t)(2048 + b) * 6 * 4608;
#pragma unroll
  for (int i = 0; i < 14; ++i) {
    int flat = tid + 512 * i;
    if (flat < 6912) {
      int h = flat / 1152, r = flat % 1152;
      int n = r >> 3, d4 = (r & 7) * 4;
      short4v vv = *(const short4v*)&qkv[vbase + (size_t)h * 4608 + n * 32 + d4];
      vt[h][d4 + 0][n] = vv[0];
      vt[h][d4 + 1][n] = vv[1];
      vt[h][d4 + 2][n] = vv[2];
      vt[h][d4 + 3][n] = vv[3];
    }
  }
  __syncthreads();    // the only barrier; LDS read-only afterwards

  int cnb6[9];
#pragma unroll
  for (int cf = 0; cf < 9; ++cf) cnb6[cf] = 6 * poscode(cf * 16 + lg * 4);
  const float* maskw = &mask[(size_t)wm * 20736];
  const size_t qb = (size_t)b * 6 * 4608;

  // units: wave w does (t=w, h=0..5); waves 0..5 additionally do (t=8, h=w)
  f32x4 mrow[9];
  int C0 = 0, q = 0;
  for (int unit = 0; unit < 7; ++unit) {
    int t, h;
    if (unit < 6) { t = wv; h = unit; }
    else { if (wv >= 6) break; t = 8; h = wv; }
    if (unit == 0 || unit == 6) {
      q = t * 16 + l15;
#pragma unroll
      for (int cf = 0; cf < 9; ++cf)
        mrow[cf] = *(const float4v*)&maskw[q * 144 + cf * 16 + lg * 4];
      C0 = (poscode(q) + 27) * 6;
    }

    const short* qrow = &qkv[qb + (size_t)h * 4608 + q * 32];
    Frag aq;
    aq.h[0] = *(const short4v*)&qrow[lg * 4];
    aq.h[1] = *(const short4v*)&qrow[lg * 4 + 16];

    f32x4 s[9];                       // s[cf][reg] = S[q][cf*16+lg*4+reg]
#pragma unroll
    for (int cf = 0; cf < 9; ++cf) {
      Frag bk;
      bk.h[0] = *(const short4v*)&k_l[h][cf * 16 + l15][lg * 4];
      bk.h[1] = *(const short4v*)&k_l[h][cf * 16 + l15][lg * 4 + 16];
      s[cf] = mfma_bf16(bk, aq, f32x4{0.f, 0.f, 0.f, 0.f});
    }
#pragma unroll
    for (int cf = 0; cf < 9; ++cf) {
      const int i0 = C0 + h - cnb6[cf];
#pragma unroll
      for (int reg = 0; reg < 4; ++reg)
        s[cf][reg] += mrow[cf][reg] + btab[i0 - 6 * reg];
    }

    // in-register softmax over k (36 regs + lanes ^16, ^32)
    float mx = s[0][0];
#pragma unroll
    for (int cf = 0; cf < 9; ++cf)
#pragma unroll
      for (int reg = 0; reg < 4; ++reg) mx = fmaxf(mx, s[cf][reg]);
    mx = fmaxf(mx, __shfl_xor(mx, 16, 64));
    mx = fmaxf(mx, __shfl_xor(mx, 32, 64));
    float sum = 0.f;
#pragma unroll
    for (int cf = 0; cf < 9; ++cf)
#pragma unroll
      for (int reg = 0; reg < 4; ++reg) {
        float e = __expf(s[cf][reg] - mx);
        s[cf][reg] = e;
        sum += e;
      }
    sum += __shfl_xor(sum, 16, 64);
    sum += __shfl_xor(sum, 32, 64);
    const float rinv = 1.0f / sum;
#pragma unroll
    for (int cf = 0; cf < 9; ++cf)
#pragma unroll
      for (int reg = 0; reg < 4; ++reg) s[cf][reg] *= rinv;

    // PV: P fragments straight from s[]
    f32x4 o0 = {0.f, 0.f, 0.f, 0.f}, o1 = {0.f, 0.f, 0.f, 0.f};
#pragma unroll
    for (int kc = 0; kc < 5; ++kc) {
      Frag ap, b0, b1;
      ap.h[0] = short4v{ f2bf(s[2 * kc][0]), f2bf(s[2 * kc][1]),
                         f2bf(s[2 * kc][2]), f2bf(s[2 * kc][3]) };
      b0.h[0] = *(const short4v*)&vt[h][l15][kc * 32 + lg * 4];
      b1.h[0] = *(const short4v*)&vt[h][16 + l15][kc * 32 + lg * 4];
      if (kc < 4) {
        ap.h[1] = short4v{ f2bf(s[2 * kc + 1][0]), f2bf(s[2 * kc + 1][1]),
                           f2bf(s[2 * kc + 1][2]), f2bf(s[2 * kc + 1][3]) };
        b0.h[1] = *(const short4v*)&vt[h][l15][kc * 32 + lg * 4 + 16];
        b1.h[1] = *(const short4v*)&vt[h][16 + l15][kc * 32 + lg * 4 + 16];
      } else {                        // K=144: zero the 144..159 half-step
        ap.h[1] = short4v{0, 0, 0, 0};
        b0.h[1] = short4v{0, 0, 0, 0};
        b1.h[1] = short4v{0, 0, 0, 0};
      }
      o0 = mfma_bf16(ap, b0, o0);
      o1 = mfma_bf16(ap, b1, o1);
    }
#pragma unroll
    for (int rr = 0; rr < 4; ++rr) {
      const int m = t * 16 + lg * 4 + rr;
      const size_t base = (size_t)(b * 144 + m) * 192 + h * 32;
      out[base + l15]      = o0[rr];
      out[base + 16 + l15] = o1[rr];
    }
  }
}

// ---------------------------------------------------------------- K3: out proj (in-place)
__global__ __launch_bounds__(256, 2) void k_oproj(
    float* __restrict__ io, const float* __restrict__ bo,
    const short* __restrict__ wto) {
  __shared__ short a_lds[64][200];
  __shared__ short bT[192][40];
  const int tid = threadIdx.x;
  const int lane = tid & 63, wv = tid >> 6;
  const int l15 = lane & 15, lg = lane >> 4;
  const int row0 = blockIdx.x * 64;

#pragma unroll
  for (int i = 0; i < 12; ++i) {
    int flat = tid + 256 * i;
    int r = flat / 48, c4 = flat % 48;
    float4v xv = *(const float4v*)&io[(size_t)(row0 + r) * 192 + c4 * 4];
    short4v sv = { f2bf(xv[0]), f2bf(xv[1]), f2bf(xv[2]), f2bf(xv[3]) };
    *(short4v*)&a_lds[r][c4 * 4] = sv;
  }

  f32x4 acc[12];
#pragma unroll
  for (int i = 0; i < 12; ++i) acc[i] = f32x4{0.f, 0.f, 0.f, 0.f};

  for (int kc = 0; kc < 6; ++kc) {
    __syncthreads();
#pragma unroll
    for (int i = 0; i < 6; ++i) {
      int flat = tid + 256 * i;             // 192 cols x 8 quads = 1536
      int c = flat >> 3, kk = (flat & 7) << 2;
      *(short4v*)&bT[c][kk] = *(const short4v*)&wto[c * 192 + kc * 32 + kk];
    }
    __syncthreads();
    Frag a;
    a.h[0] = *(const short4v*)&a_lds[wv * 16 + l15][kc * 32 + lg * 4];
    a.h[1] = *(const short4v*)&a_lds[wv * 16 + l15][kc * 32 + lg * 4 + 16];
#pragma unroll
    for (int cf = 0; cf < 12; ++cf) {
      Frag bw;
      bw.h[0] = *(const short4v*)&bT[cf * 16 + l15][lg * 4];
      bw.h[1] = *(const short4v*)&bT[cf * 16 + l15][lg * 4 + 16];
      acc[cf] = mfma_bf16(a, bw, acc[cf]);
    }
  }

#pragma unroll
  for (int cf = 0; cf < 12; ++cf) {
    int c = cf * 16 + l15;
    float bias = bo[c];
#pragma unroll
    for (int r = 0; r < 4; ++r) {
      int g = row0 + wv * 16 + lg * 4 + r;
      io[(size_t)g * 192 + c] = acc[cf][r] + bias;
    }
  }
}

extern "C" void kernel_launch(void* const* d_in, const int* in_sizes, int n_in,
                              void* d_out, int out_size, void* d_ws, size_t ws_size,
                              hipStream_t stream) {
  const float* x    = (const float*)d_in[0];
  const float* mask = (const float*)d_in[1];
  const float* wqkv = (const float*)d_in[2];
  const float* bqkv = (const float*)d_in[3];
  const float* wo   = (const float*)d_in[4];
  const float* bo   = (const float*)d_in[5];
  const float* btab = (const float*)d_in[6];
  float* out = (float*)d_out;

  short* wtq = (short*)d_ws;                 //    110,592 shorts
  short* wto = wtq + 110592;                 //     36,864 shorts
  short* qkv = wto + 36864;                  // 84,934,656 shorts (162 MB)

  k_transpose_w<<<576, 256, 0, stream>>>(wqkv, wo, wtq, wto);
  k_qkv<<<2304, 256, 0, stream>>>(x, bqkv, wtq, qkv);
  k_attn<<<1024, 512, 0, stream>>>(qkv, mask, btab, out);
  k_oproj<<<2304, 256, 0, stream>>>(out, bo, wto);
}